// Round 3
// baseline (622.503 us; speedup 1.0000x reference)
//
#include <hip/hip_runtime.h>
#include <hip/hip_bf16.h>
#include <stdint.h>

// Problem constants
#define T_ 4
#define B_ 32
#define C_ 512
#define N_ 256
#define HEADS_ 8

typedef __attribute__((ext_vector_type(8))) short bf16x8;      // 8 bf16 (4 VGPR) MFMA operand
typedef __attribute__((ext_vector_type(4))) float float4_;
typedef __attribute__((ext_vector_type(16))) float f32x16;     // 32x32 MFMA accumulator

__device__ __forceinline__ unsigned short f2bf(float x){       // RNE f32->bf16
  unsigned int u = __float_as_uint(x);
  u += 0x7FFFu + ((u >> 16) & 1u);
  return (unsigned short)(u >> 16);
}
__device__ __forceinline__ float bf2f(unsigned short b){
  return __uint_as_float(((unsigned int)b) << 16);
}

// swizzled LDS fragment read: row-major tile with 128B rows, byte ^= ((row&7)<<4)
__device__ __forceinline__ bf16x8 lds_frag(const unsigned short* base, int row, int cb){
  return *(const bf16x8*)((const char*)base + row * 128 + (cb ^ ((row & 7) << 4)));
}

// ---------------------------------------------------------------------------
// prep: fold BN into weights (w' = w * g/sqrt(var+eps)), split into bf16
// hi+mid+lo (3-term: |err| <= 2^-27 relative, better than fp32), and build
// per-channel bias (b - m*rs; for p: (pbias-m)*rs + b).
// ---------------------------------------------------------------------------
struct PrepArgs {
  const float* w[4];
  const float* g[4];
  const float* bb[4];
  const float* m[4];
  const float* v[4];
  const float* pbias;
};

__global__ __launch_bounds__(256) void prep_kernel(PrepArgs pa,
    unsigned short* __restrict__ whi, unsigned short* __restrict__ wmid,
    unsigned short* __restrict__ wlo, float* __restrict__ biasv)
{
  int idx = blockIdx.x * 256 + threadIdx.x;      // < 4*512*512
  int mat = idx >> 18;
  int rem = idx & 0x3FFFF;
  int o = rem >> 9;
  float g   = pa.g[mat][o];
  float var = pa.v[mat][o];
  float mm  = pa.m[mat][o];
  float bof = pa.bb[mat][o];
  float rs  = g / sqrtf(var + 1e-5f);
  float wv  = pa.w[mat][rem] * rs;
  unsigned short hi = f2bf(wv);
  float r1 = wv - bf2f(hi);              // exact (nearby subtraction)
  unsigned short mid = f2bf(r1);
  float r2 = r1 - bf2f(mid);             // exact
  unsigned short lo = f2bf(r2);
  whi[idx] = hi;
  wmid[idx] = mid;
  wlo[idx] = lo;
  if ((rem & 511) == 0){
    float bias = (mat < 3) ? (bof - mm * rs) : ((pa.pbias[o] - mm) * rs + bof);
    biasv[mat * 512 + o] = bias;
  }
}

// ---------------------------------------------------------------------------
// K1: proj LIF over t (tau=2, vth=1, hard reset; bitwise-identical fp32 ops
// to reference) + transpose [t,b,c,n]->[t,b,n,c]. Spikes as bf16 bits.
// Write phase vectorized: each lane packs 8 contiguous c into one uint4 store
// (1KiB per wave-instruction vs 128B scalar).
// ---------------------------------------------------------------------------
__global__ __launch_bounds__(256) void lif_tr_kernel(const float* __restrict__ x,
                                                     unsigned short* __restrict__ xsT)
{
  __shared__ alignas(16) unsigned short tile[64][66];   // pad 66: 2-way bank max
  int bid = blockIdx.x;
  int b  = bid & 31;
  int r  = bid >> 5;
  int ct = r & 7;        // c tile (64)
  int nt = r >> 3;       // n tile (64), 0..3
  int tid = threadIdx.x;
  int col = tid & 63;
  int rq  = tid >> 6;    // 0..3
  float v[16];
#pragma unroll
  for (int i = 0; i < 16; i++) v[i] = 0.0f;
  const float* xb = x + (size_t)b * C_ * N_ + (size_t)ct * 64 * N_ + nt * 64;
  unsigned short* ob = xsT + (size_t)b * N_ * C_ + (size_t)nt * 64 * C_ + ct * 64;
  for (int t = 0; t < T_; t++){
    const float* xt = xb + (size_t)t * B_ * C_ * N_;
#pragma unroll
    for (int i = 0; i < 16; i++){
      int row = i * 4 + rq;                       // c-local
      float xx = xt[(size_t)row * N_ + col];      // coalesced over col=n
      float vv = v[i];
      vv = vv + (xx - vv) * 0.5f;                 // v += (x-v)/tau, tau=2
      bool sp = (vv - 1.0f) >= 0.0f;
      tile[row][col] = sp ? 0x3F80 : 0;
      v[i] = sp ? 0.0f : vv;                      // hard reset
    }
    __syncthreads();
    unsigned short* ot = ob + (size_t)t * B_ * N_ * C_;
#pragma unroll
    for (int p = 0; p < 2; p++){
      int nrow = p * 32 + (tid >> 3);             // n-local
      int c0   = (tid & 7) * 8;                   // c-local octet base
      unsigned int w0 = (unsigned int)tile[c0 + 0][nrow] | ((unsigned int)tile[c0 + 1][nrow] << 16);
      unsigned int w1 = (unsigned int)tile[c0 + 2][nrow] | ((unsigned int)tile[c0 + 3][nrow] << 16);
      unsigned int w2 = (unsigned int)tile[c0 + 4][nrow] | ((unsigned int)tile[c0 + 5][nrow] << 16);
      unsigned int w3 = (unsigned int)tile[c0 + 6][nrow] | ((unsigned int)tile[c0 + 7][nrow] << 16);
      uint4 v4{w0, w1, w2, w3};
      *(uint4*)(ot + (size_t)nrow * C_ + c0) = v4;   // 16B, 16B-aligned
    }
    __syncthreads();
  }
}

// ---------------------------------------------------------------------------
// K2: q/k/v branch: y = W'.xs (+bias) -> LIF (vth=1) -> spikes.
// Block = (branch, o-tile 64, b). Tile [64 o][256 n], full K=512, t-loop
// inside (LIF state in regs). 4 waves, wave tile [64 o][64 n],
// mfma 32x32x16 bf16, THREE weight terms accumulate into the same acc.
// q written transposed [t,b,n,c]; k,v written [t,b,c,n].
// ---------------------------------------------------------------------------
__global__ __launch_bounds__(256, 2) void branch_kernel(
    const unsigned short* __restrict__ whi, const unsigned short* __restrict__ wmid,
    const unsigned short* __restrict__ wlo,
    const float* __restrict__ biasv, const unsigned short* __restrict__ xsT,
    unsigned short* __restrict__ qT, unsigned short* __restrict__ kS,
    unsigned short* __restrict__ vS)
{
  __shared__ alignas(16) unsigned short As[3][64 * 64];   // [term][o][c] swizzled, 24 KB
  __shared__ alignas(16) unsigned short Bs[256 * 64];     // [n][c] swizzled, 32 KB (also bounce)
  __shared__ alignas(16) float bias_lds[64];

  int bid = blockIdx.x;
  int b  = bid & 31;          // b fastest -> blocks sharing b land on same XCD
  int r2 = bid >> 5;
  int ot = r2 & 7;
  int br = r2 >> 3;           // 0=q 1=k 2=v
  int o0 = ot * 64;
  int tid = threadIdx.x;
  int w    = tid >> 6;        // wave 0..3 -> n range w*64
  int lane = tid & 63;
  int lm = lane & 31;
  int hi = lane >> 5;

  if (tid < 64) bias_lds[tid] = biasv[br * 512 + o0 + tid];

  const unsigned short* wsrc[3] = { whi + (size_t)br * 262144,
                                    wmid + (size_t)br * 262144,
                                    wlo + (size_t)br * 262144 };

  f32x16 acc[2][2];
  float  st[2][2][16];
#pragma unroll
  for (int a = 0; a < 2; a++)
#pragma unroll
    for (int c = 0; c < 2; c++)
#pragma unroll
      for (int i = 0; i < 16; i++) st[a][c][i] = 0.0f;

  for (int t = 0; t < T_; t++){
#pragma unroll
    for (int a = 0; a < 2; a++)
#pragma unroll
      for (int c = 0; c < 2; c++)
#pragma unroll
        for (int i = 0; i < 16; i++) acc[a][c][i] = 0.0f;

    const unsigned short* bsrc = xsT + (size_t)(t * B_ + b) * N_ * C_;

    for (int kk = 0; kk < 8; kk++){             // K = 8 * 64
      __syncthreads();
      // stage A tiles (hi/mid/lo terms): 64 rows x 128B each
#pragma unroll
      for (int term = 0; term < 3; term++){
#pragma unroll
        for (int p = 0; p < 2; p++){
          int chunk = p * 256 + tid;
          int row = chunk >> 3, cb = (chunk & 7) * 16;
          uint4 val = *(const uint4*)((const char*)(wsrc[term] + (size_t)(o0 + row) * 512 + kk * 64) + cb);
          *(uint4*)((char*)As[term] + row * 128 + (cb ^ ((row & 7) << 4))) = val;
        }
      }
      // stage B tile: 256 rows x 128B
      uint4 tmp[8];
#pragma unroll
      for (int p = 0; p < 8; p++){
        int chunk = p * 256 + tid;
        int row = chunk >> 3, cb = (chunk & 7) * 16;
        tmp[p] = *(const uint4*)((const char*)(bsrc + (size_t)row * C_ + kk * 64) + cb);
      }
#pragma unroll
      for (int p = 0; p < 8; p++){
        int chunk = p * 256 + tid;
        int row = chunk >> 3, cb = (chunk & 7) * 16;
        *(uint4*)((char*)Bs + row * 128 + (cb ^ ((row & 7) << 4))) = tmp[p];
      }
      __syncthreads();
#pragma unroll
      for (int ks = 0; ks < 4; ks++){
        int cb = ks * 32 + 16 * hi;
        bf16x8 b0  = lds_frag(Bs, w * 64 + lm,      cb);
        bf16x8 b1  = lds_frag(Bs, w * 64 + 32 + lm, cb);
#pragma unroll
        for (int term = 0; term < 3; term++){
          bf16x8 a0 = lds_frag(As[term], lm,      cb);
          bf16x8 a1 = lds_frag(As[term], 32 + lm, cb);
          acc[0][0] = __builtin_amdgcn_mfma_f32_32x32x16_bf16(a0, b0, acc[0][0], 0, 0, 0);
          acc[0][1] = __builtin_amdgcn_mfma_f32_32x32x16_bf16(a0, b1, acc[0][1], 0, 0, 0);
          acc[1][0] = __builtin_amdgcn_mfma_f32_32x32x16_bf16(a1, b0, acc[1][0], 0, 0, 0);
          acc[1][1] = __builtin_amdgcn_mfma_f32_32x32x16_bf16(a1, b1, acc[1][1], 0, 0, 0);
        }
      }
    }
    __syncthreads();
    // epilogue: bias + LIF -> spike bits into bounce buffer (Bs)
#pragma unroll
    for (int mf = 0; mf < 2; mf++){
#pragma unroll
      for (int nf = 0; nf < 2; nf++){
        int n_loc = w * 64 + nf * 32 + lm;
#pragma unroll
        for (int rq = 0; rq < 4; rq++){
          float4_ b4 = *(const float4_*)&bias_lds[mf * 32 + 8 * rq + 4 * hi];
#pragma unroll
          for (int rr = 0; rr < 4; rr++){
            int r = rq * 4 + rr;
            int o_loc = mf * 32 + rr + 8 * rq + 4 * hi;
            float y = acc[mf][nf][r] + b4[rr];
            float vv = st[mf][nf][r];
            vv = vv + (y - vv) * 0.5f;
            bool sp = (vv - 1.0f) >= 0.0f;
            st[mf][nf][r] = sp ? 0.0f : vv;
            unsigned short sb = sp ? 0x3F80 : 0;
            if (br == 0){  // q: bounce as [n][o] swizzled
              *(unsigned short*)((char*)Bs + n_loc * 128 + ((o_loc * 2) ^ ((n_loc & 7) << 4))) = sb;
            } else {       // k/v: bounce as [o][n]
              *(unsigned short*)((char*)Bs + o_loc * 512 + n_loc * 2) = sb;
            }
          }
        }
      }
    }
    __syncthreads();
    if (br == 0){
      unsigned short* dst = qT + (size_t)(t * B_ + b) * N_ * C_ + o0;
#pragma unroll
      for (int p = 0; p < 8; p++){
        int chunk = p * 256 + tid;
        int row = chunk >> 3, cb = (chunk & 7) * 16;
        uint4 val = *(const uint4*)((const char*)Bs + row * 128 + (cb ^ ((row & 7) << 4)));
        *(uint4*)((char*)dst + (size_t)row * 1024 + cb) = val;
      }
    } else {
      unsigned short* dst = (br == 1 ? kS : vS) + ((size_t)(t * B_ + b) * C_ + o0) * N_;
#pragma unroll
      for (int p = 0; p < 8; p++){
        int chunk = p * 256 + tid;
        int row = chunk >> 5, nb = (chunk & 31) * 16;
        uint4 val = *(const uint4*)((const char*)Bs + row * 512 + nb);
        *(uint4*)((char*)dst + (size_t)row * 512 + nb) = val;
      }
    }
  }
}

// ---------------------------------------------------------------------------
// K3: per (b,h): kv = K.V^T over n (exact integer counts <=256, exact bf16),
// a^T = Q_T . kv^T, scale 0.125 (exact), attn LIF (vth=0.5, dyadic-exact)
// -> spikes to sT [t,b,n,c].
// ---------------------------------------------------------------------------
__global__ __launch_bounds__(256, 2) void attn_kernel(
    const unsigned short* __restrict__ qT, const unsigned short* __restrict__ kS,
    const unsigned short* __restrict__ vS, unsigned short* __restrict__ sT)
{
  __shared__ alignas(16) unsigned short Ks[64 * 64];    // [d][n-chunk] swizzled, 8 KB
  __shared__ alignas(16) unsigned short Vs[64 * 64];    // [e][n-chunk] swizzled, 8 KB
  __shared__ alignas(16) unsigned short KVT[64 * 64];   // [e][d] swizzled bf16, 8 KB
  __shared__ alignas(16) unsigned short Qs[256 * 64];   // [n][d] swizzled, 32 KB (also s bounce)

  int bid = blockIdx.x;
  int b = bid & 31;
  int h = bid >> 5;
  int tid = threadIdx.x;
  int w = tid >> 6;          // wave 0..3
  int lane = tid & 63;
  int lm = lane & 31, hi = lane >> 5;
  int mfk = w >> 1, nfk = w & 1;   // kv fragment owned by this wave

  float stA[2][2][16];
#pragma unroll
  for (int a = 0; a < 2; a++)
#pragma unroll
  for (int c = 0; c < 2; c++)
#pragma unroll
  for (int i = 0; i < 16; i++) stA[a][c][i] = 0.0f;

  for (int t = 0; t < T_; t++){
    const unsigned short* ksrc = kS + ((size_t)(t * B_ + b) * C_ + h * 64) * N_;
    const unsigned short* vsrc = vS + ((size_t)(t * B_ + b) * C_ + h * 64) * N_;
    const unsigned short* qsrc = qT + (size_t)(t * B_ + b) * N_ * C_ + h * 64;
    unsigned short* sdst = sT + (size_t)(t * B_ + b) * N_ * C_ + h * 64;

    f32x16 kvacc;
#pragma unroll
    for (int i = 0; i < 16; i++) kvacc[i] = 0.0f;

    for (int ch = 0; ch < 4; ch++){           // n in chunks of 64
      __syncthreads();
#pragma unroll
      for (int p = 0; p < 2; p++){
        int chunk = p * 256 + tid;
        int row = chunk >> 3, cb = (chunk & 7) * 16;
        uint4 kval = *(const uint4*)((const char*)ksrc + (size_t)row * 512 + ch * 128 + cb);
        uint4 vval = *(const uint4*)((const char*)vsrc + (size_t)row * 512 + ch * 128 + cb);
        *(uint4*)((char*)Ks + row * 128 + (cb ^ ((row & 7) << 4))) = kval;
        *(uint4*)((char*)Vs + row * 128 + (cb ^ ((row & 7) << 4))) = vval;
      }
      __syncthreads();
#pragma unroll
      for (int ki = 0; ki < 4; ki++){
        int cb = ki * 32 + 16 * hi;
        bf16x8 ak = lds_frag(Ks, mfk * 32 + lm, cb);
        bf16x8 bv = lds_frag(Vs, nfk * 32 + lm, cb);
        kvacc = __builtin_amdgcn_mfma_f32_32x32x16_bf16(ak, bv, kvacc, 0, 0, 0);
      }
    }
    // write kv transposed [e][d] as bf16 (exact: integer counts <= 256)
    {
      int e = nfk * 32 + lm;
#pragma unroll
      for (int r = 0; r < 16; r++){
        int d = mfk * 32 + (r & 3) + 8 * (r >> 2) + 4 * hi;
        *(unsigned short*)((char*)KVT + e * 128 + ((d * 2) ^ ((e & 7) << 4))) = f2bf(kvacc[r]);
      }
    }
    // stage Q_T tile [256 n][64 d]
#pragma unroll
    for (int p = 0; p < 8; p++){
      int chunk = p * 256 + tid;
      int row = chunk >> 3, cb = (chunk & 7) * 16;
      uint4 qv = *(const uint4*)((const char*)qsrc + (size_t)row * 1024 + cb);
      *(uint4*)((char*)Qs + row * 128 + (cb ^ ((row & 7) << 4))) = qv;
    }
    __syncthreads();
    // a[n][e] = sum_d QT[n][d] * kv[d][e]
    f32x16 aacc[2][2];
#pragma unroll
    for (int a = 0; a < 2; a++)
#pragma unroll
    for (int c = 0; c < 2; c++)
#pragma unroll
    for (int i = 0; i < 16; i++) aacc[a][c][i] = 0.0f;
#pragma unroll
    for (int ki = 0; ki < 4; ki++){
      int cb = ki * 32 + 16 * hi;
      bf16x8 aq0 = lds_frag(Qs, w * 64 + lm,      cb);
      bf16x8 aq1 = lds_frag(Qs, w * 64 + 32 + lm, cb);
      bf16x8 b0  = lds_frag(KVT, lm,      cb);
      bf16x8 b1  = lds_frag(KVT, 32 + lm, cb);
      aacc[0][0] = __builtin_amdgcn_mfma_f32_32x32x16_bf16(aq0, b0, aacc[0][0], 0, 0, 0);
      aacc[0][1] = __builtin_amdgcn_mfma_f32_32x32x16_bf16(aq0, b1, aacc[0][1], 0, 0, 0);
      aacc[1][0] = __builtin_amdgcn_mfma_f32_32x32x16_bf16(aq1, b0, aacc[1][0], 0, 0, 0);
      aacc[1][1] = __builtin_amdgcn_mfma_f32_32x32x16_bf16(aq1, b1, aacc[1][1], 0, 0, 0);
    }
    // attn LIF (vth=0.5) -> spike bits bounced into Qs (each wave owns its rows)
#pragma unroll
    for (int mf = 0; mf < 2; mf++){
#pragma unroll
      for (int nf = 0; nf < 2; nf++){
        int e_loc = nf * 32 + lm;
#pragma unroll
        for (int r = 0; r < 16; r++){
          float aval = aacc[mf][nf][r] * 0.125f;
          float vv = stA[mf][nf][r];
          vv = vv + (aval - vv) * 0.5f;
          bool sp = (vv - 0.5f) >= 0.0f;
          stA[mf][nf][r] = sp ? 0.0f : vv;
          int n_loc = w * 64 + mf * 32 + (r & 3) + 8 * (r >> 2) + 4 * hi;
          *(unsigned short*)((char*)Qs + n_loc * 128 + ((e_loc * 2) ^ ((n_loc & 7) << 4))) = sp ? 0x3F80 : 0;
        }
      }
    }
    __syncthreads();
#pragma unroll
    for (int p = 0; p < 8; p++){
      int chunk = p * 256 + tid;
      int row = chunk >> 3, cb = (chunk & 7) * 16;
      uint4 val = *(const uint4*)((const char*)Qs + row * 128 + (cb ^ ((row & 7) << 4)));
      *(uint4*)((char*)sdst + (size_t)row * 1024 + cb) = val;
    }
  }
}

// ---------------------------------------------------------------------------
// K4: projection: out = W'p . s + bias'p (BN + p_bias folded). fp32 output.
// Block = (o-tile 64, t, b), tile [64 o][256 n]. 3-term weights.
// ---------------------------------------------------------------------------
__global__ __launch_bounds__(256, 2) void proj_kernel(
    const unsigned short* __restrict__ whi, const unsigned short* __restrict__ wmid,
    const unsigned short* __restrict__ wlo,
    const float* __restrict__ biasv, const unsigned short* __restrict__ sT,
    float* __restrict__ out)
{
  __shared__ alignas(16) unsigned short As[3][64 * 64];
  __shared__ alignas(16) unsigned short Bs[256 * 64];
  __shared__ alignas(16) float bias_lds[64];

  int bid = blockIdx.x;
  int tb = bid & 127;          // tb fastest -> same (t,b) blocks share XCD/L2
  int ot = bid >> 7;
  int t = tb >> 5, b = tb & 31;
  int o0 = ot * 64;
  int tid = threadIdx.x;
  int w = tid >> 6, lane = tid & 63, lm = lane & 31, hi = lane >> 5;

  if (tid < 64) bias_lds[tid] = biasv[3 * 512 + o0 + tid];

  const unsigned short* wsrc[3] = { whi + (size_t)3 * 262144,
                                    wmid + (size_t)3 * 262144,
                                    wlo + (size_t)3 * 262144 };
  const unsigned short* bsrc = sT + (size_t)(t * B_ + b) * N_ * C_;

  f32x16 acc[2][2];
#pragma unroll
  for (int a = 0; a < 2; a++)
#pragma unroll
    for (int c = 0; c < 2; c++)
#pragma unroll
      for (int i = 0; i < 16; i++) acc[a][c][i] = 0.0f;

  for (int kk = 0; kk < 8; kk++){
    __syncthreads();
#pragma unroll
    for (int term = 0; term < 3; term++){
#pragma unroll
      for (int p = 0; p < 2; p++){
        int chunk = p * 256 + tid;
        int row = chunk >> 3, cb = (chunk & 7) * 16;
        uint4 val = *(const uint4*)((const char*)(wsrc[term] + (size_t)(o0 + row) * 512 + kk * 64) + cb);
        *(uint4*)((char*)As[term] + row * 128 + (cb ^ ((row & 7) << 4))) = val;
      }
    }
    uint4 tmp[8];
#pragma unroll
    for (int p = 0; p < 8; p++){
      int chunk = p * 256 + tid;
      int row = chunk >> 3, cb = (chunk & 7) * 16;
      tmp[p] = *(const uint4*)((const char*)(bsrc + (size_t)row * C_ + kk * 64) + cb);
    }
#pragma unroll
    for (int p = 0; p < 8; p++){
      int chunk = p * 256 + tid;
      int row = chunk >> 3, cb = (chunk & 7) * 16;
      *(uint4*)((char*)Bs + row * 128 + (cb ^ ((row & 7) << 4))) = tmp[p];
    }
    __syncthreads();
#pragma unroll
    for (int ks = 0; ks < 4; ks++){
      int cb = ks * 32 + 16 * hi;
      bf16x8 b0  = lds_frag(Bs, w * 64 + lm,      cb);
      bf16x8 b1  = lds_frag(Bs, w * 64 + 32 + lm, cb);
#pragma unroll
      for (int term = 0; term < 3; term++){
        bf16x8 a0 = lds_frag(As[term], lm,      cb);
        bf16x8 a1 = lds_frag(As[term], 32 + lm, cb);
        acc[0][0] = __builtin_amdgcn_mfma_f32_32x32x16_bf16(a0, b0, acc[0][0], 0, 0, 0);
        acc[0][1] = __builtin_amdgcn_mfma_f32_32x32x16_bf16(a0, b1, acc[0][1], 0, 0, 0);
        acc[1][0] = __builtin_amdgcn_mfma_f32_32x32x16_bf16(a1, b0, acc[1][0], 0, 0, 0);
        acc[1][1] = __builtin_amdgcn_mfma_f32_32x32x16_bf16(a1, b1, acc[1][1], 0, 0, 0);
      }
    }
  }
  float* dst = out + ((size_t)(t * B_ + b) * C_ + o0) * N_;
#pragma unroll
  for (int mf = 0; mf < 2; mf++){
#pragma unroll
    for (int nf = 0; nf < 2; nf++){
      int n_loc = w * 64 + nf * 32 + lm;
#pragma unroll
      for (int rq = 0; rq < 4; rq++){
        float4_ b4 = *(const float4_*)&bias_lds[mf * 32 + 8 * rq + 4 * hi];
#pragma unroll
        for (int rr = 0; rr < 4; rr++){
          int o_loc = mf * 32 + rr + 8 * rq + 4 * hi;
          dst[(size_t)o_loc * N_ + n_loc] = acc[mf][nf][rq * 4 + rr] + b4[rr];
        }
      }
    }
  }
}

// ---------------------------------------------------------------------------
// launch
// ---------------------------------------------------------------------------
extern "C" void kernel_launch(void* const* d_in, const int* in_sizes, int n_in,
                              void* d_out, int out_size, void* d_ws, size_t ws_size,
                              hipStream_t stream) {
  const float* x = (const float*)d_in[0];
  PrepArgs pa;
  pa.w[0]  = (const float*)d_in[1];
  pa.g[0]  = (const float*)d_in[2];
  pa.bb[0] = (const float*)d_in[3];
  pa.m[0]  = (const float*)d_in[4];
  pa.v[0]  = (const float*)d_in[5];
  pa.w[1]  = (const float*)d_in[6];
  pa.g[1]  = (const float*)d_in[7];
  pa.bb[1] = (const float*)d_in[8];
  pa.m[1]  = (const float*)d_in[9];
  pa.v[1]  = (const float*)d_in[10];
  pa.w[2]  = (const float*)d_in[11];
  pa.g[2]  = (const float*)d_in[12];
  pa.bb[2] = (const float*)d_in[13];
  pa.m[2]  = (const float*)d_in[14];
  pa.v[2]  = (const float*)d_in[15];
  pa.w[3]  = (const float*)d_in[16];
  pa.pbias = (const float*)d_in[17];
  pa.g[3]  = (const float*)d_in[18];
  pa.bb[3] = (const float*)d_in[19];
  pa.m[3]  = (const float*)d_in[20];
  pa.v[3]  = (const float*)d_in[21];

  // workspace layout (~140 MB)
  char* ws = (char*)d_ws;
  unsigned short* whi  = (unsigned short*)(ws);                               // 2 MB
  unsigned short* wmid = (unsigned short*)(ws + 0x200000);                    // 2 MB
  unsigned short* wlo  = (unsigned short*)(ws + 0x400000);                    // 2 MB
  float*          biasv= (float*)(ws + 0x600000);                             // 8 KB
  unsigned short* xsT  = (unsigned short*)(ws + 0x610000);                    // 32 MiB [t,b,n,c]
  unsigned short* sTp  = xsT;                                                 // alias: xs dead before s written
  unsigned short* qT   = (unsigned short*)(ws + 0x610000 + (size_t)32*1024*1024);
  unsigned short* kS   = (unsigned short*)(ws + 0x610000 + (size_t)64*1024*1024);
  unsigned short* vS   = (unsigned short*)(ws + 0x610000 + (size_t)96*1024*1024);

  prep_kernel<<<4096, 256, 0, stream>>>(pa, whi, wmid, wlo, biasv);
  lif_tr_kernel<<<1024, 256, 0, stream>>>(x, xsT);
  branch_kernel<<<768, 256, 0, stream>>>(whi, wmid, wlo, biasv, xsT, qT, kS, vS);
  attn_kernel<<<256, 256, 0, stream>>>(qT, kS, vS, sTp);
  proj_kernel<<<1024, 256, 0, stream>>>(whi, wmid, wlo, biasv, sTp, (float*)d_out);
}

// Round 4
// 404.484 us; speedup vs baseline: 1.5390x; 1.5390x over previous
//
#include <hip/hip_runtime.h>
#include <hip/hip_bf16.h>
#include <stdint.h>

// Problem constants
#define T_ 4
#define B_ 32
#define C_ 512
#define N_ 256
#define HEADS_ 8

typedef __attribute__((ext_vector_type(8))) short bf16x8;      // 8 bf16 (4 VGPR) MFMA operand
typedef __attribute__((ext_vector_type(4))) float float4_;
typedef __attribute__((ext_vector_type(16))) float f32x16;     // 32x32 MFMA accumulator

__device__ __forceinline__ unsigned short f2bf(float x){       // RNE f32->bf16
  unsigned int u = __float_as_uint(x);
  u += 0x7FFFu + ((u >> 16) & 1u);
  return (unsigned short)(u >> 16);
}
__device__ __forceinline__ float bf2f(unsigned short b){
  return __uint_as_float(((unsigned int)b) << 16);
}

// async global->LDS, 16B per lane. LDS dest = wave-uniform base + lane*16
// (we pass per-lane ptrs that satisfy exactly that). Global src is per-lane.
__device__ __forceinline__ void gload16(const void* g, void* l){
  __builtin_amdgcn_global_load_lds(
      (const __attribute__((address_space(1))) unsigned int*)g,
      (__attribute__((address_space(3))) unsigned int*)l, 16, 0, 0);
}

// swizzled LDS fragment read: row-major tile with 128B rows, byte ^= ((row&7)<<4)
__device__ __forceinline__ bf16x8 lds_frag(const unsigned short* base, int row, int cb){
  return *(const bf16x8*)((const char*)base + row * 128 + (cb ^ ((row & 7) << 4)));
}

// ---------------------------------------------------------------------------
// prep: fold BN into weights (w' = w * g/sqrt(var+eps)), split into bf16
// hi+mid+lo (3-term: |err| <= 2^-27 relative, better than fp32), and build
// per-channel bias (b - m*rs; for p: (pbias-m)*rs + b).
// ---------------------------------------------------------------------------
struct PrepArgs {
  const float* w[4];
  const float* g[4];
  const float* bb[4];
  const float* m[4];
  const float* v[4];
  const float* pbias;
};

__global__ __launch_bounds__(256) void prep_kernel(PrepArgs pa,
    unsigned short* __restrict__ whi, unsigned short* __restrict__ wmid,
    unsigned short* __restrict__ wlo, float* __restrict__ biasv)
{
  int idx = blockIdx.x * 256 + threadIdx.x;      // < 4*512*512
  int mat = idx >> 18;
  int rem = idx & 0x3FFFF;
  int o = rem >> 9;
  float g   = pa.g[mat][o];
  float var = pa.v[mat][o];
  float mm  = pa.m[mat][o];
  float bof = pa.bb[mat][o];
  float rs  = g / sqrtf(var + 1e-5f);
  float wv  = pa.w[mat][rem] * rs;
  unsigned short hi = f2bf(wv);
  float r1 = wv - bf2f(hi);              // exact (nearby subtraction)
  unsigned short mid = f2bf(r1);
  float r2 = r1 - bf2f(mid);             // exact
  unsigned short lo = f2bf(r2);
  whi[idx] = hi;
  wmid[idx] = mid;
  wlo[idx] = lo;
  if ((rem & 511) == 0){
    float bias = (mat < 3) ? (bof - mm * rs) : ((pa.pbias[o] - mm) * rs + bof);
    biasv[mat * 512 + o] = bias;
  }
}

// ---------------------------------------------------------------------------
// K1: proj LIF over t (tau=2, vth=1, hard reset; bitwise-identical fp32 ops
// to reference) + transpose [t,b,c,n]->[t,b,n,c]. Spikes as bf16 bits.
// ---------------------------------------------------------------------------
__global__ __launch_bounds__(256) void lif_tr_kernel(const float* __restrict__ x,
                                                     unsigned short* __restrict__ xsT)
{
  __shared__ alignas(16) unsigned short tile[64][66];   // pad 66: 2-way bank max
  int bid = blockIdx.x;
  int b  = bid & 31;
  int r  = bid >> 5;
  int ct = r & 7;        // c tile (64)
  int nt = r >> 3;       // n tile (64), 0..3
  int tid = threadIdx.x;
  int col = tid & 63;
  int rq  = tid >> 6;    // 0..3
  float v[16];
#pragma unroll
  for (int i = 0; i < 16; i++) v[i] = 0.0f;
  const float* xb = x + (size_t)b * C_ * N_ + (size_t)ct * 64 * N_ + nt * 64;
  unsigned short* ob = xsT + (size_t)b * N_ * C_ + (size_t)nt * 64 * C_ + ct * 64;
  for (int t = 0; t < T_; t++){
    const float* xt = xb + (size_t)t * B_ * C_ * N_;
#pragma unroll
    for (int i = 0; i < 16; i++){
      int row = i * 4 + rq;                       // c-local
      float xx = xt[(size_t)row * N_ + col];      // coalesced over col=n
      float vv = v[i];
      vv = vv + (xx - vv) * 0.5f;                 // v += (x-v)/tau, tau=2
      bool sp = (vv - 1.0f) >= 0.0f;
      tile[row][col] = sp ? 0x3F80 : 0;
      v[i] = sp ? 0.0f : vv;                      // hard reset
    }
    __syncthreads();
    unsigned short* ot = ob + (size_t)t * B_ * N_ * C_;
#pragma unroll
    for (int p = 0; p < 2; p++){
      int nrow = p * 32 + (tid >> 3);             // n-local
      int c0   = (tid & 7) * 8;                   // c-local octet base
      unsigned int w0 = (unsigned int)tile[c0 + 0][nrow] | ((unsigned int)tile[c0 + 1][nrow] << 16);
      unsigned int w1 = (unsigned int)tile[c0 + 2][nrow] | ((unsigned int)tile[c0 + 3][nrow] << 16);
      unsigned int w2 = (unsigned int)tile[c0 + 4][nrow] | ((unsigned int)tile[c0 + 5][nrow] << 16);
      unsigned int w3 = (unsigned int)tile[c0 + 6][nrow] | ((unsigned int)tile[c0 + 7][nrow] << 16);
      uint4 v4{w0, w1, w2, w3};
      *(uint4*)(ot + (size_t)nrow * C_ + c0) = v4;   // 16B, 16B-aligned
    }
    __syncthreads();
  }
}

// ---------------------------------------------------------------------------
// K2: q/k/v branch: y = W'.xs (+bias) -> LIF (vth=1) -> spikes.
// Staging via global_load_lds(16B): linear LDS dest, inverse-swizzled global
// source -> LDS image identical to the reg-staged version.
// q written transposed [t,b,n,c] (b64-packed bounce); k,v written [t,b,c,n].
// ---------------------------------------------------------------------------
__global__ __launch_bounds__(256, 2) void branch_kernel(
    const unsigned short* __restrict__ whi, const unsigned short* __restrict__ wmid,
    const unsigned short* __restrict__ wlo,
    const float* __restrict__ biasv, const unsigned short* __restrict__ xsT,
    unsigned short* __restrict__ qT, unsigned short* __restrict__ kS,
    unsigned short* __restrict__ vS)
{
  __shared__ alignas(16) unsigned short As[3][64 * 64];   // [term][o][c] swizzled, 24 KB
  __shared__ alignas(16) unsigned short Bs[256 * 64];     // [n][c] swizzled, 32 KB (also bounce)
  __shared__ alignas(16) float bias_lds[64];

  int bid = blockIdx.x;
  int b  = bid & 31;          // b fastest -> blocks sharing b land on same XCD
  int r2 = bid >> 5;
  int ot = r2 & 7;
  int br = r2 >> 3;           // 0=q 1=k 2=v
  int o0 = ot * 64;
  int tid = threadIdx.x;
  int w    = tid >> 6;        // wave 0..3 -> n range w*64
  int lane = tid & 63;
  int lm = lane & 31;
  int hi = lane >> 5;

  if (tid < 64) bias_lds[tid] = biasv[br * 512 + o0 + tid];

  const unsigned short* wsrc[3] = { whi + (size_t)br * 262144,
                                    wmid + (size_t)br * 262144,
                                    wlo + (size_t)br * 262144 };

  f32x16 acc[2][2];
  float  st[2][2][16];
#pragma unroll
  for (int a = 0; a < 2; a++)
#pragma unroll
    for (int c = 0; c < 2; c++)
#pragma unroll
      for (int i = 0; i < 16; i++) st[a][c][i] = 0.0f;

  for (int t = 0; t < T_; t++){
#pragma unroll
    for (int a = 0; a < 2; a++)
#pragma unroll
      for (int c = 0; c < 2; c++)
#pragma unroll
        for (int i = 0; i < 16; i++) acc[a][c][i] = 0.0f;

    const unsigned short* bsrc = xsT + (size_t)(t * B_ + b) * N_ * C_;

    for (int kk = 0; kk < 8; kk++){             // K = 8 * 64
      __syncthreads();                           // prior reads of As/Bs done
      // stage A tiles (hi/mid/lo): linear LDS dest, pre-swizzled source
#pragma unroll
      for (int term = 0; term < 3; term++){
#pragma unroll
        for (int p = 0; p < 2; p++){
          int chunk = p * 256 + tid;
          int row = chunk >> 3, cb = (chunk & 7) * 16;
          gload16((const char*)(wsrc[term] + (size_t)(o0 + row) * 512 + kk * 64)
                      + (cb ^ ((row & 7) << 4)),
                  (char*)As[term] + chunk * 16);
        }
      }
      // stage B tile
#pragma unroll
      for (int p = 0; p < 8; p++){
        int chunk = p * 256 + tid;
        int row = chunk >> 3, cb = (chunk & 7) * 16;
        gload16((const char*)(bsrc + (size_t)row * C_ + kk * 64)
                    + (cb ^ ((row & 7) << 4)),
                (char*)Bs + chunk * 16);
      }
      __syncthreads();                           // vmcnt(0) drained by compiler
#pragma unroll
      for (int ks = 0; ks < 4; ks++){
        int cb = ks * 32 + 16 * hi;
        bf16x8 b0  = lds_frag(Bs, w * 64 + lm,      cb);
        bf16x8 b1  = lds_frag(Bs, w * 64 + 32 + lm, cb);
#pragma unroll
        for (int term = 0; term < 3; term++){
          bf16x8 a0 = lds_frag(As[term], lm,      cb);
          bf16x8 a1 = lds_frag(As[term], 32 + lm, cb);
          acc[0][0] = __builtin_amdgcn_mfma_f32_32x32x16_bf16(a0, b0, acc[0][0], 0, 0, 0);
          acc[0][1] = __builtin_amdgcn_mfma_f32_32x32x16_bf16(a0, b1, acc[0][1], 0, 0, 0);
          acc[1][0] = __builtin_amdgcn_mfma_f32_32x32x16_bf16(a1, b0, acc[1][0], 0, 0, 0);
          acc[1][1] = __builtin_amdgcn_mfma_f32_32x32x16_bf16(a1, b1, acc[1][1], 0, 0, 0);
        }
      }
    }
    __syncthreads();
    // epilogue: bias + LIF -> spike bits into bounce buffer (Bs)
#pragma unroll
    for (int mf = 0; mf < 2; mf++){
#pragma unroll
      for (int nf = 0; nf < 2; nf++){
        int n_loc = w * 64 + nf * 32 + lm;
#pragma unroll
        for (int rq = 0; rq < 4; rq++){
          float4_ b4 = *(const float4_*)&bias_lds[mf * 32 + 8 * rq + 4 * hi];
          unsigned short sb[4];
#pragma unroll
          for (int rr = 0; rr < 4; rr++){
            int r = rq * 4 + rr;
            float y = acc[mf][nf][r] + b4[rr];
            float vv = st[mf][nf][r];
            vv = vv + (y - vv) * 0.5f;
            bool sp = (vv - 1.0f) >= 0.0f;
            st[mf][nf][r] = sp ? 0.0f : vv;
            sb[rr] = sp ? 0x3F80 : 0;
          }
          if (br == 0){   // q: [n][o] swizzled, 4 consecutive o -> one b64
            unsigned int u0 = (unsigned int)sb[0] | ((unsigned int)sb[1] << 16);
            unsigned int u1 = (unsigned int)sb[2] | ((unsigned int)sb[3] << 16);
            int o0b = (mf * 32 + 8 * rq + 4 * hi) * 2;   // 8B-aligned
            *(unsigned long long*)((char*)Bs + n_loc * 128 + (o0b ^ ((n_loc & 7) << 4)))
                = ((unsigned long long)u1 << 32) | u0;
          } else {        // k/v: [o][n], contiguous across lanes
#pragma unroll
            for (int rr = 0; rr < 4; rr++){
              int o_loc = mf * 32 + rr + 8 * rq + 4 * hi;
              *(unsigned short*)((char*)Bs + o_loc * 512 + n_loc * 2) = sb[rr];
            }
          }
        }
      }
    }
    __syncthreads();
    if (br == 0){
      unsigned short* dst = qT + (size_t)(t * B_ + b) * N_ * C_ + o0;
#pragma unroll
      for (int p = 0; p < 8; p++){
        int chunk = p * 256 + tid;
        int row = chunk >> 3, cb = (chunk & 7) * 16;
        uint4 val = *(const uint4*)((const char*)Bs + row * 128 + (cb ^ ((row & 7) << 4)));
        *(uint4*)((char*)dst + (size_t)row * 1024 + cb) = val;
      }
    } else {
      unsigned short* dst = (br == 1 ? kS : vS) + ((size_t)(t * B_ + b) * C_ + o0) * N_;
#pragma unroll
      for (int p = 0; p < 8; p++){
        int chunk = p * 256 + tid;
        int row = chunk >> 5, nb = (chunk & 31) * 16;
        uint4 val = *(const uint4*)((const char*)Bs + row * 512 + nb);
        *(uint4*)((char*)dst + (size_t)row * 512 + nb) = val;
      }
    }
  }
}

// ---------------------------------------------------------------------------
// K3: per (b,h): kv = K.V^T over n (exact integer counts <=256, exact bf16),
// a = Q.kv, scale 0.125 (exact), attn LIF (vth=0.5, dyadic-exact)
// -> spikes to sT [t,b,n,c].
// ---------------------------------------------------------------------------
__global__ __launch_bounds__(256, 2) void attn_kernel(
    const unsigned short* __restrict__ qT, const unsigned short* __restrict__ kS,
    const unsigned short* __restrict__ vS, unsigned short* __restrict__ sT)
{
  __shared__ alignas(16) unsigned short Ks[64 * 64];    // [d][n-chunk] swizzled, 8 KB
  __shared__ alignas(16) unsigned short Vs[64 * 64];    // [e][n-chunk] swizzled, 8 KB
  __shared__ alignas(16) unsigned short KVT[64 * 64];   // [e][d] swizzled bf16, 8 KB
  __shared__ alignas(16) unsigned short Qs[256 * 64];   // [n][d] swizzled, 32 KB (also s bounce)

  int bid = blockIdx.x;
  int b = bid & 31;
  int h = bid >> 5;
  int tid = threadIdx.x;
  int w = tid >> 6;          // wave 0..3
  int lane = tid & 63;
  int lm = lane & 31, hi = lane >> 5;
  int mfk = w >> 1, nfk = w & 1;   // kv fragment owned by this wave

  float stA[2][2][16];
#pragma unroll
  for (int a = 0; a < 2; a++)
#pragma unroll
  for (int c = 0; c < 2; c++)
#pragma unroll
  for (int i = 0; i < 16; i++) stA[a][c][i] = 0.0f;

  for (int t = 0; t < T_; t++){
    const unsigned short* ksrc = kS + ((size_t)(t * B_ + b) * C_ + h * 64) * N_;
    const unsigned short* vsrc = vS + ((size_t)(t * B_ + b) * C_ + h * 64) * N_;
    const unsigned short* qsrc = qT + (size_t)(t * B_ + b) * N_ * C_ + h * 64;
    unsigned short* sdst = sT + (size_t)(t * B_ + b) * N_ * C_ + h * 64;

    f32x16 kvacc;
#pragma unroll
    for (int i = 0; i < 16; i++) kvacc[i] = 0.0f;

    for (int ch = 0; ch < 4; ch++){           // n in chunks of 64
      __syncthreads();
#pragma unroll
      for (int p = 0; p < 2; p++){
        int chunk = p * 256 + tid;
        int row = chunk >> 3, cb = (chunk & 7) * 16;
        int so = (cb ^ ((row & 7) << 4));
        gload16((const char*)ksrc + (size_t)row * 512 + ch * 128 + so,
                (char*)Ks + chunk * 16);
        gload16((const char*)vsrc + (size_t)row * 512 + ch * 128 + so,
                (char*)Vs + chunk * 16);
      }
      __syncthreads();
#pragma unroll
      for (int ki = 0; ki < 4; ki++){
        int cb = ki * 32 + 16 * hi;
        bf16x8 ak = lds_frag(Ks, mfk * 32 + lm, cb);
        bf16x8 bv = lds_frag(Vs, nfk * 32 + lm, cb);
        kvacc = __builtin_amdgcn_mfma_f32_32x32x16_bf16(ak, bv, kvacc, 0, 0, 0);
      }
    }
    // write kv transposed [e][d] as bf16 (exact: integer counts <= 256),
    // 4 consecutive d packed into one b64
    {
      int e = nfk * 32 + lm;
#pragma unroll
      for (int rq = 0; rq < 4; rq++){
        unsigned int u0 = (unsigned int)f2bf(kvacc[rq * 4 + 0])
                        | ((unsigned int)f2bf(kvacc[rq * 4 + 1]) << 16);
        unsigned int u1 = (unsigned int)f2bf(kvacc[rq * 4 + 2])
                        | ((unsigned int)f2bf(kvacc[rq * 4 + 3]) << 16);
        int d0b = (mfk * 32 + 8 * rq + 4 * hi) * 2;   // 8B-aligned
        *(unsigned long long*)((char*)KVT + e * 128 + (d0b ^ ((e & 7) << 4)))
            = ((unsigned long long)u1 << 32) | u0;
      }
    }
    // stage Q tile [256 n][64 d]
#pragma unroll
    for (int p = 0; p < 8; p++){
      int chunk = p * 256 + tid;
      int row = chunk >> 3, cb = (chunk & 7) * 16;
      gload16((const char*)qsrc + (size_t)row * 1024 + (cb ^ ((row & 7) << 4)),
              (char*)Qs + chunk * 16);
    }
    __syncthreads();
    // a[n][e] = sum_d Q[n][d] * kv[d][e]
    f32x16 aacc[2][2];
#pragma unroll
    for (int a = 0; a < 2; a++)
#pragma unroll
    for (int c = 0; c < 2; c++)
#pragma unroll
    for (int i = 0; i < 16; i++) aacc[a][c][i] = 0.0f;
#pragma unroll
    for (int ki = 0; ki < 4; ki++){
      int cb = ki * 32 + 16 * hi;
      bf16x8 aq0 = lds_frag(Qs, w * 64 + lm,      cb);
      bf16x8 aq1 = lds_frag(Qs, w * 64 + 32 + lm, cb);
      bf16x8 b0  = lds_frag(KVT, lm,      cb);
      bf16x8 b1  = lds_frag(KVT, 32 + lm, cb);
      aacc[0][0] = __builtin_amdgcn_mfma_f32_32x32x16_bf16(aq0, b0, aacc[0][0], 0, 0, 0);
      aacc[0][1] = __builtin_amdgcn_mfma_f32_32x32x16_bf16(aq0, b1, aacc[0][1], 0, 0, 0);
      aacc[1][0] = __builtin_amdgcn_mfma_f32_32x32x16_bf16(aq1, b0, aacc[1][0], 0, 0, 0);
      aacc[1][1] = __builtin_amdgcn_mfma_f32_32x32x16_bf16(aq1, b1, aacc[1][1], 0, 0, 0);
    }
    // attn LIF (vth=0.5) -> spike bits bounced into Qs (each wave owns its rows)
#pragma unroll
    for (int mf = 0; mf < 2; mf++){
#pragma unroll
      for (int nf = 0; nf < 2; nf++){
        int e_loc = nf * 32 + lm;
#pragma unroll
        for (int r = 0; r < 16; r++){
          float aval = aacc[mf][nf][r] * 0.125f;
          float vv = stA[mf][nf][r];
          vv = vv + (aval - vv) * 0.5f;
          bool sp = (vv - 0.5f) >= 0.0f;
          stA[mf][nf][r] = sp ? 0.0f : vv;
          int n_loc = w * 64 + mf * 32 + (r & 3) + 8 * (r >> 2) + 4 * hi;
          *(unsigned short*)((char*)Qs + n_loc * 128 + ((e_loc * 2) ^ ((n_loc & 7) << 4))) = sp ? 0x3F80 : 0;
        }
      }
    }
    __syncthreads();
#pragma unroll
    for (int p = 0; p < 8; p++){
      int chunk = p * 256 + tid;
      int row = chunk >> 3, cb = (chunk & 7) * 16;
      uint4 val = *(const uint4*)((const char*)Qs + row * 128 + (cb ^ ((row & 7) << 4)));
      *(uint4*)((char*)sdst + (size_t)row * 1024 + cb) = val;
    }
  }
}

// ---------------------------------------------------------------------------
// K4: projection: out = W'p . s + bias'p (BN + p_bias folded). fp32 output.
// Block = (o-tile 64, t, b), tile [64 o][256 n]. 3-term weights, gload_lds.
// ---------------------------------------------------------------------------
__global__ __launch_bounds__(256, 2) void proj_kernel(
    const unsigned short* __restrict__ whi, const unsigned short* __restrict__ wmid,
    const unsigned short* __restrict__ wlo,
    const float* __restrict__ biasv, const unsigned short* __restrict__ sT,
    float* __restrict__ out)
{
  __shared__ alignas(16) unsigned short As[3][64 * 64];
  __shared__ alignas(16) unsigned short Bs[256 * 64];
  __shared__ alignas(16) float bias_lds[64];

  int bid = blockIdx.x;
  int tb = bid & 127;          // tb fastest -> same (t,b) blocks share XCD/L2
  int ot = bid >> 7;
  int t = tb >> 5, b = tb & 31;
  int o0 = ot * 64;
  int tid = threadIdx.x;
  int w = tid >> 6, lane = tid & 63, lm = lane & 31, hi = lane >> 5;

  if (tid < 64) bias_lds[tid] = biasv[3 * 512 + o0 + tid];

  const unsigned short* wsrc[3] = { whi + (size_t)3 * 262144,
                                    wmid + (size_t)3 * 262144,
                                    wlo + (size_t)3 * 262144 };
  const unsigned short* bsrc = sT + (size_t)(t * B_ + b) * N_ * C_;

  f32x16 acc[2][2];
#pragma unroll
  for (int a = 0; a < 2; a++)
#pragma unroll
    for (int c = 0; c < 2; c++)
#pragma unroll
      for (int i = 0; i < 16; i++) acc[a][c][i] = 0.0f;

  for (int kk = 0; kk < 8; kk++){
    __syncthreads();
#pragma unroll
    for (int term = 0; term < 3; term++){
#pragma unroll
      for (int p = 0; p < 2; p++){
        int chunk = p * 256 + tid;
        int row = chunk >> 3, cb = (chunk & 7) * 16;
        gload16((const char*)(wsrc[term] + (size_t)(o0 + row) * 512 + kk * 64)
                    + (cb ^ ((row & 7) << 4)),
                (char*)As[term] + chunk * 16);
      }
    }
#pragma unroll
    for (int p = 0; p < 8; p++){
      int chunk = p * 256 + tid;
      int row = chunk >> 3, cb = (chunk & 7) * 16;
      gload16((const char*)(bsrc + (size_t)row * C_ + kk * 64)
                  + (cb ^ ((row & 7) << 4)),
              (char*)Bs + chunk * 16);
    }
    __syncthreads();
#pragma unroll
    for (int ks = 0; ks < 4; ks++){
      int cb = ks * 32 + 16 * hi;
      bf16x8 b0  = lds_frag(Bs, w * 64 + lm,      cb);
      bf16x8 b1  = lds_frag(Bs, w * 64 + 32 + lm, cb);
#pragma unroll
      for (int term = 0; term < 3; term++){
        bf16x8 a0 = lds_frag(As[term], lm,      cb);
        bf16x8 a1 = lds_frag(As[term], 32 + lm, cb);
        acc[0][0] = __builtin_amdgcn_mfma_f32_32x32x16_bf16(a0, b0, acc[0][0], 0, 0, 0);
        acc[0][1] = __builtin_amdgcn_mfma_f32_32x32x16_bf16(a0, b1, acc[0][1], 0, 0, 0);
        acc[1][0] = __builtin_amdgcn_mfma_f32_32x32x16_bf16(a1, b0, acc[1][0], 0, 0, 0);
        acc[1][1] = __builtin_amdgcn_mfma_f32_32x32x16_bf16(a1, b1, acc[1][1], 0, 0, 0);
      }
    }
  }
  float* dst = out + ((size_t)(t * B_ + b) * C_ + o0) * N_;
#pragma unroll
  for (int mf = 0; mf < 2; mf++){
#pragma unroll
    for (int nf = 0; nf < 2; nf++){
      int n_loc = w * 64 + nf * 32 + lm;
#pragma unroll
      for (int rq = 0; rq < 4; rq++){
        float4_ b4 = *(const float4_*)&bias_lds[mf * 32 + 8 * rq + 4 * hi];
#pragma unroll
        for (int rr = 0; rr < 4; rr++){
          int o_loc = mf * 32 + rr + 8 * rq + 4 * hi;
          dst[(size_t)o_loc * N_ + n_loc] = acc[mf][nf][rq * 4 + rr] + b4[rr];
        }
      }
    }
  }
}

// ---------------------------------------------------------------------------
// launch
// ---------------------------------------------------------------------------
extern "C" void kernel_launch(void* const* d_in, const int* in_sizes, int n_in,
                              void* d_out, int out_size, void* d_ws, size_t ws_size,
                              hipStream_t stream) {
  const float* x = (const float*)d_in[0];
  PrepArgs pa;
  pa.w[0]  = (const float*)d_in[1];
  pa.g[0]  = (const float*)d_in[2];
  pa.bb[0] = (const float*)d_in[3];
  pa.m[0]  = (const float*)d_in[4];
  pa.v[0]  = (const float*)d_in[5];
  pa.w[1]  = (const float*)d_in[6];
  pa.g[1]  = (const float*)d_in[7];
  pa.bb[1] = (const float*)d_in[8];
  pa.m[1]  = (const float*)d_in[9];
  pa.v[1]  = (const float*)d_in[10];
  pa.w[2]  = (const float*)d_in[11];
  pa.g[2]  = (const float*)d_in[12];
  pa.bb[2] = (const float*)d_in[13];
  pa.m[2]  = (const float*)d_in[14];
  pa.v[2]  = (const float*)d_in[15];
  pa.w[3]  = (const float*)d_in[16];
  pa.pbias = (const float*)d_in[17];
  pa.g[3]  = (const float*)d_in[18];
  pa.bb[3] = (const float*)d_in[19];
  pa.m[3]  = (const float*)d_in[20];
  pa.v[3]  = (const float*)d_in[21];

  // workspace layout (~140 MB)
  char* ws = (char*)d_ws;
  unsigned short* whi  = (unsigned short*)(ws);                               // 2 MB
  unsigned short* wmid = (unsigned short*)(ws + 0x200000);                    // 2 MB
  unsigned short* wlo  = (unsigned short*)(ws + 0x400000);                    // 2 MB
  float*          biasv= (float*)(ws + 0x600000);                             // 8 KB
  unsigned short* xsT  = (unsigned short*)(ws + 0x610000);                    // 32 MiB [t,b,n,c]
  unsigned short* sTp  = xsT;                                                 // alias: xs dead before s written
  unsigned short* qT   = (unsigned short*)(ws + 0x610000 + (size_t)32*1024*1024);
  unsigned short* kS   = (unsigned short*)(ws + 0x610000 + (size_t)64*1024*1024);
  unsigned short* vS   = (unsigned short*)(ws + 0x610000 + (size_t)96*1024*1024);

  prep_kernel<<<4096, 256, 0, stream>>>(pa, whi, wmid, wlo, biasv);
  lif_tr_kernel<<<1024, 256, 0, stream>>>(x, xsT);
  branch_kernel<<<768, 256, 0, stream>>>(whi, wmid, wlo, biasv, xsT, qT, kS, vS);
  attn_kernel<<<256, 256, 0, stream>>>(qT, kS, vS, sTp);
  proj_kernel<<<1024, 256, 0, stream>>>(whi, wmid, wlo, biasv, sTp, (float*)d_out);
}